// Round 1
// baseline (222.222 us; speedup 1.0000x reference)
//
#include <hip/hip_runtime.h>

#define HIDDEN 128
#define P_NUM 8
#define PLEN 4
#define ETYPES 2
#define BN 32                      // nodes per block (100000 = 3125*32, no tail)
#define AP 136                     // bf16 row pitch in LDS (128 + 8 pad -> 2-way-free banks)

typedef __attribute__((ext_vector_type(8))) short short8;
typedef __attribute__((ext_vector_type(4))) float floatx4;

__device__ __forceinline__ unsigned short f2bf(float x) {
  unsigned int u = __float_as_uint(x);
  u += 0x7FFFu + ((u >> 16) & 1u);
  return (unsigned short)(u >> 16);
}

// generic f32 -> bf16 (used for W_fc)
__global__ __launch_bounds__(256) void cvt_bf16(const float* __restrict__ in,
                                                unsigned short* __restrict__ out, int n4) {
  int i = blockIdx.x * blockDim.x + threadIdx.x;
  if (i < n4) {
    float4 f = ((const float4*)in)[i];
    ((ushort4*)out)[i] = make_ushort4(f2bf(f.x), f2bf(f.y), f2bf(f.z), f2bf(f.w));
  }
}

// ---- Kernel A: Y = feats @ [W0^T | W1^T]  (N x 256), fused per-(node,half) uint8 quant ----
// Yq[m][e*128+o] = rint(Y*127/absmax)+128 (biased u8); sY[m*2+e] = absmax/127.
__global__ __launch_bounds__(256, 4) void gemm_quant(
    const float* __restrict__ feats,
    const unsigned short* __restrict__ wfc_bf,   // bf16, 128 x 256 (row o, col e*128+c)
    unsigned char* __restrict__ Yq,              // u8, N x 256
    float* __restrict__ sY,                      // f32, N x 2
    int n_nodes)
{
  __shared__ __align__(16) unsigned short Abf[BN * AP];   // 8704 B; overlaid by u8 bounce later
  __shared__ float rowmax[ETYPES][2][BN];                 // [half][wave-of-pair][node]

  const int tid = threadIdx.x;
  const int n0 = blockIdx.x * BN;

  // stage feats f32 -> bf16 LDS (16 elems / thread)
  {
    const int row = tid >> 3;
    const int c0 = (tid & 7) * 16;
    int rg = n0 + row; if (rg >= n_nodes) rg = n_nodes - 1;
    const float* src = feats + (size_t)rg * HIDDEN + c0;
    float4 v0 = ((const float4*)src)[0];
    float4 v1 = ((const float4*)src)[1];
    float4 v2 = ((const float4*)src)[2];
    float4 v3 = ((const float4*)src)[3];
    short8 u0, u1;
    u0[0]=(short)f2bf(v0.x); u0[1]=(short)f2bf(v0.y); u0[2]=(short)f2bf(v0.z); u0[3]=(short)f2bf(v0.w);
    u0[4]=(short)f2bf(v1.x); u0[5]=(short)f2bf(v1.y); u0[6]=(short)f2bf(v1.z); u0[7]=(short)f2bf(v1.w);
    u1[0]=(short)f2bf(v2.x); u1[1]=(short)f2bf(v2.y); u1[2]=(short)f2bf(v2.z); u1[3]=(short)f2bf(v2.w);
    u1[4]=(short)f2bf(v3.x); u1[5]=(short)f2bf(v3.y); u1[6]=(short)f2bf(v3.z); u1[7]=(short)f2bf(v3.w);
    *(short8*)&Abf[row * AP + c0] = u0;
    *(short8*)&Abf[row * AP + c0 + 8] = u1;
  }
  __syncthreads();

  const int wv = tid >> 6, lane = tid & 63, q = lane >> 4, rr = lane & 15;

  floatx4 acc[2][4];
  #pragma unroll
  for (int mt = 0; mt < 2; ++mt)
    #pragma unroll
    for (int jt = 0; jt < 4; ++jt)
      acc[mt][jt] = (floatx4){0.f, 0.f, 0.f, 0.f};

  // wave wv owns output cols j = wv*64 + jt*16 + rr  (j in [0,256))
  #pragma unroll
  for (int kk = 0; kk < 4; ++kk) {
    short8 af[2];
    af[0] = *(const short8*)&Abf[rr * AP + kk * 32 + q * 8];
    af[1] = *(const short8*)&Abf[(16 + rr) * AP + kk * 32 + q * 8];
    #pragma unroll
    for (int jt = 0; jt < 4; ++jt) {
      const int j = wv * 64 + jt * 16 + rr;
      const short8 bf = *(const short8*)&wfc_bf[(size_t)(j & 127) * (ETYPES * HIDDEN)
                                                + (j >> 7) * HIDDEN + kk * 32 + q * 8];
      acc[0][jt] = __builtin_amdgcn_mfma_f32_16x16x32_bf16(af[0], bf, acc[0][jt], 0, 0, 0);
      acc[1][jt] = __builtin_amdgcn_mfma_f32_16x16x32_bf16(af[1], bf, acc[1][jt], 0, 0, 0);
    }
  }

  // --- per-(node,half) absmax ---
  const int e = wv >> 1;
  float mx[2][4];
  #pragma unroll
  for (int mt = 0; mt < 2; ++mt)
    #pragma unroll
    for (int reg = 0; reg < 4; ++reg)
      mx[mt][reg] = fmaxf(fmaxf(fabsf(acc[mt][0][reg]), fabsf(acc[mt][1][reg])),
                          fmaxf(fabsf(acc[mt][2][reg]), fabsf(acc[mt][3][reg])));
  #pragma unroll
  for (int d = 1; d < 16; d <<= 1)
    #pragma unroll
    for (int mt = 0; mt < 2; ++mt)
      #pragma unroll
      for (int reg = 0; reg < 4; ++reg)
        mx[mt][reg] = fmaxf(mx[mt][reg], __shfl_xor(mx[mt][reg], d));
  if (rr == 0) {
    #pragma unroll
    for (int mt = 0; mt < 2; ++mt)
      #pragma unroll
      for (int reg = 0; reg < 4; ++reg)
        rowmax[e][wv & 1][mt * 16 + q * 4 + reg] = mx[mt][reg];
  }
  __syncthreads();   // also fences all Abf reads before the u8 overlay below

  unsigned char* Yb = (unsigned char*)Abf;   // 32 x 256 u8 bounce (8 KB, fits in Abf)
  #pragma unroll
  for (int mt = 0; mt < 2; ++mt)
    #pragma unroll
    for (int reg = 0; reg < 4; ++reg) {
      const int node = mt * 16 + q * 4 + reg;
      const float full = fmaxf(rowmax[e][0][node], rowmax[e][1][node]);
      const float inv = (full > 0.f) ? 127.f * __builtin_amdgcn_rcpf(full) : 0.f;
      #pragma unroll
      for (int jt = 0; jt < 4; ++jt) {
        const int u = (int)rintf(acc[mt][jt][reg] * inv) + 128;
        Yb[node * 256 + wv * 64 + jt * 16 + rr] = (unsigned char)u;
      }
      if (rr == 0 && (wv & 1) == 0 && (n0 + node) < n_nodes)
        sY[(size_t)(n0 + node) * ETYPES + e] = full * (1.f / 127.f);
    }
  __syncthreads();

  // coalesced copyout (32 B / thread)
  {
    const int node = tid >> 3;
    const int off = (tid & 7) * 32;
    if (n0 + node < n_nodes) {
      const uint4* s = (const uint4*)&Yb[node * 256 + off];
      uint4 a = s[0], b = s[1];
      uint4* d = (uint4*)&Yq[(size_t)(n0 + node) * 256 + off];
      d[0] = a; d[1] = b;
    }
  }
}

// ---- Kernel B: pure gather-scale-accumulate. No LDS, no barriers, no MFMA. ----
// out[n][o] = relu( sum_{p,l} (w[t_p,l]/cnt_{t_p}) * (Yq[idx][t_p*128+o]-128) * sY[idx*2+t_p] )
__global__ __launch_bounds__(256, 6) void impeller_gather(
    const unsigned char* __restrict__ Yq,
    const float* __restrict__ sY,
    const int* __restrict__ paths,
    const int* __restrict__ ptypes,
    const float* __restrict__ pweights,
    float* __restrict__ out,
    int n_nodes)
{
  const int tid = threadIdx.x;
  const int wv = tid >> 6, lane = tid & 63, g = lane >> 4, r = lane & 15;
  const int nbase = blockIdx.x * BN + wv * 8;   // this wave's 8 nodes
  const int roff = r * 8;                       // 8 dims per lane

  // per-thread path coefficients (group g owns paths g and g+4; j<4 -> path g, j>=4 -> path g+4)
  int tpv[P_NUM]; int cnt0 = 0;
  #pragma unroll
  for (int p = 0; p < P_NUM; ++p) { tpv[p] = ptypes[p]; cnt0 += (tpv[p] == 0); }
  const int cnt1 = P_NUM - cnt0;
  const float ic0 = cnt0 ? 1.f / (float)cnt0 : 0.f;
  const float ic1 = cnt1 ? 1.f / (float)cnt1 : 0.f;

  float cj[8]; int boff[8]; int hb[8];
  #pragma unroll
  for (int j = 0; j < 8; ++j) {
    const int p = g + 4 * (j >> 2), l = j & 3, t = tpv[p];
    cj[j] = pweights[t * PLEN + l] * (t == 0 ? ic0 : ic1);
    hb[j] = t;
    boff[j] = t * HIDDEN + roff;    // byte offset within a Yq row
  }

  #pragma unroll 1
  for (int it = 0; it < 4; ++it) {
    int nA = nbase + it * 2;
    int nB = nA + 1;
    const int nAc = (nA < n_nodes) ? nA : (n_nodes - 1);
    const int nBc = (nB < n_nodes) ? nB : (n_nodes - 1);
    const int4 iA0 = *(const int4*)&paths[((size_t)g * n_nodes + nAc) * PLEN];
    const int4 iA1 = *(const int4*)&paths[((size_t)(g + 4) * n_nodes + nAc) * PLEN];
    const int4 iB0 = *(const int4*)&paths[((size_t)g * n_nodes + nBc) * PLEN];
    const int4 iB1 = *(const int4*)&paths[((size_t)(g + 4) * n_nodes + nBc) * PLEN];
    const int ia[8] = {iA0.x, iA0.y, iA0.z, iA0.w, iA1.x, iA1.y, iA1.z, iA1.w};
    const int ib[8] = {iB0.x, iB0.y, iB0.z, iB0.w, iB1.x, iB1.y, iB1.z, iB1.w};

    // 32 loads in flight: 16 row fragments (8 B) + 16 scale broadcasts
    uint2 fa[8], fb[8];
    float sa[8], sb[8];
    #pragma unroll
    for (int j = 0; j < 8; ++j) {
      fa[j] = *(const uint2*)(Yq + (size_t)ia[j] * 256 + boff[j]);
      sa[j] = sY[(size_t)ia[j] * ETYPES + hb[j]];
    }
    #pragma unroll
    for (int j = 0; j < 8; ++j) {
      fb[j] = *(const uint2*)(Yq + (size_t)ib[j] * 256 + boff[j]);
      sb[j] = sY[(size_t)ib[j] * ETYPES + hb[j]];
    }

    #pragma unroll
    for (int half = 0; half < 2; ++half) {
      float acc[8] = {0.f, 0.f, 0.f, 0.f, 0.f, 0.f, 0.f, 0.f};
      float corr = 0.f;
      #pragma unroll
      for (int j = 0; j < 8; ++j) {
        const uint2 f = half ? fb[j] : fa[j];
        const float cs = cj[j] * (half ? sb[j] : sa[j]);
        corr += cs;
        #pragma unroll
        for (int d = 0; d < 4; ++d) {
          acc[d]     += cs * (float)((f.x >> (8 * d)) & 0xFFu);   // v_cvt_f32_ubyte_d + fma
          acc[4 + d] += cs * (float)((f.y >> (8 * d)) & 0xFFu);
        }
      }
      // single cross-group reduction (4 groups -> full sum in all lanes)
      #pragma unroll
      for (int k = 0; k < 8; ++k) {
        acc[k] += __shfl_xor(acc[k], 16);
        acc[k] += __shfl_xor(acc[k], 32);
      }
      corr += __shfl_xor(corr, 16);
      corr += __shfl_xor(corr, 32);
      const float c128 = 128.f * corr;

      if (g < 2) {   // g0 stores dims roff..+3, g1 stores roff+4..+7
        const int nn = half ? nB : nA;
        float4 o4;
        o4.x = fmaxf(acc[g * 4 + 0] - c128, 0.f);
        o4.y = fmaxf(acc[g * 4 + 1] - c128, 0.f);
        o4.z = fmaxf(acc[g * 4 + 2] - c128, 0.f);
        o4.w = fmaxf(acc[g * 4 + 3] - c128, 0.f);
        if (nn < n_nodes)
          *(float4*)&out[(size_t)nn * HIDDEN + roff + g * 4] = o4;
      }
    }
  }
}

extern "C" void kernel_launch(void* const* d_in, const int* in_sizes, int n_in,
                              void* d_out, int out_size, void* d_ws, size_t ws_size,
                              hipStream_t stream) {
  const float* feats    = (const float*)d_in[0];
  const int*   paths    = (const int*)d_in[1];
  const int*   ptypes   = (const int*)d_in[2];
  const float* pweights = (const float*)d_in[3];
  const float* Wfc      = (const float*)d_in[4];
  float* out = (float*)d_out;

  const int n_nodes = in_sizes[0] / HIDDEN;          // 100000
  const int blocks = (n_nodes + BN - 1) / BN;

  // ws layout: [Yq u8 N*256][sY f32 N*2][wfc bf16 128*256]
  char* ws = (char*)d_ws;
  unsigned char* Yq = (unsigned char*)ws;
  float* sY = (float*)(ws + (size_t)n_nodes * 256);                                  // 25.6 MB in
  unsigned short* wfc_bf = (unsigned short*)(ws + (size_t)n_nodes * 256
                                                + (size_t)n_nodes * ETYPES * sizeof(float));

  const int wfc4 = in_sizes[4] / 4;                  // 32768/4
  hipLaunchKernelGGL(cvt_bf16, dim3((wfc4 + 255) / 256), dim3(256), 0, stream,
                     Wfc, wfc_bf, wfc4);
  hipLaunchKernelGGL(gemm_quant, dim3(blocks), dim3(256), 0, stream,
                     feats, wfc_bf, Yq, sY, n_nodes);
  hipLaunchKernelGGL(impeller_gather, dim3(blocks), dim3(256), 0, stream,
                     Yq, sY, paths, ptypes, pweights, out, n_nodes);
}